// Round 1
// baseline (285.925 us; speedup 1.0000x reference)
//
#include <hip/hip_runtime.h>

#define BB 2
#define NN 16384
#define MM 4096
#define C1 128
#define C2 256
#define CG 1024
#define CT 1411   // 3 + 128 + 256 + 1024

// 8192 blocks (one per (b,m)), 256 threads.
__global__ __launch_bounds__(256) void p2p_fused(
    const float* __restrict__ P,   // [B,3,N]
    const float* __restrict__ Q,   // [B,3,M]
    const float* __restrict__ F1,  // [B,C1,N]
    const float* __restrict__ F2,  // [B,C2,N]
    const float* __restrict__ G,   // [B,CG]
    float* __restrict__ out)       // [B,M,M]
{
    const int t  = threadIdx.x;
    const int bm = blockIdx.x;
    const int b  = bm >> 12;        // M = 4096 = 2^12
    const int m  = bm & (MM - 1);

    const float* Pb = P + (size_t)b * 3 * NN;
    const float qx = Q[(size_t)b * 3 * MM + 0 * MM + m];
    const float qy = Q[(size_t)b * 3 * MM + 1 * MM + m];
    const float qz = Q[(size_t)b * 3 * MM + 2 * MM + m];
    // q2 in numpy order: (x*x + y*y) + z*z, no fma
    const float q2 = __fadd_rn(__fadd_rn(__fmul_rn(qx, qx), __fmul_rn(qy, qy)),
                               __fmul_rn(qz, qz));

    // per-thread top-3 (sorted ascending), stable: strict < keeps lower index
    float bd0 = 3.402823466e+38f, bd1 = 3.402823466e+38f, bd2 = 3.402823466e+38f;
    int   bi0 = 0x7fffffff, bi1 = 0x7fffffff, bi2 = 0x7fffffff;

    #pragma unroll 4
    for (int n = t; n < NN; n += 256) {
        float px = Pb[n];
        float py = Pb[NN + n];
        float pz = Pb[2 * NN + n];
        float p2 = __fadd_rn(__fadd_rn(__fmul_rn(px, px), __fmul_rn(py, py)),
                             __fmul_rn(pz, pz));
        float qp = __fadd_rn(__fadd_rn(__fmul_rn(qx, px), __fmul_rn(qy, py)),
                             __fmul_rn(qz, pz));
        // d2 = (q2 + p2) - 2*qp  (expanded form, exactly like reference _knn_idx)
        float d2 = __fsub_rn(__fadd_rn(q2, p2), __fadd_rn(qp, qp));
        if (d2 < bd2) {
            if (d2 < bd1) {
                if (d2 < bd0) { bd2 = bd1; bi2 = bi1; bd1 = bd0; bi1 = bi0; bd0 = d2; bi0 = n; }
                else          { bd2 = bd1; bi2 = bi1; bd1 = d2;  bi1 = n; }
            } else            { bd2 = d2;  bi2 = n; }
        }
    }

    __shared__ float sd[256][3];
    __shared__ int   si[256][3];
    sd[t][0] = bd0; sd[t][1] = bd1; sd[t][2] = bd2;
    si[t][0] = bi0; si[t][1] = bi1; si[t][2] = bi2;
    __syncthreads();

    // tree merge of sorted triples; tie-break: lower index wins (top_k stability)
    for (int off = 128; off >= 1; off >>= 1) {
        if (t < off) {
            float A[3]  = { sd[t][0], sd[t][1], sd[t][2] };
            int   AI[3] = { si[t][0], si[t][1], si[t][2] };
            float Bv[3] = { sd[t + off][0], sd[t + off][1], sd[t + off][2] };
            int   BI[3] = { si[t + off][0], si[t + off][1], si[t + off][2] };
            float rd[3]; int ri[3];
            int pa = 0, pb = 0;
            #pragma unroll
            for (int r = 0; r < 3; r++) {
                bool ta = (A[pa] < Bv[pb]) || (A[pa] == Bv[pb] && AI[pa] < BI[pb]);
                if (ta) { rd[r] = A[pa];  ri[r] = AI[pa]; pa++; }
                else    { rd[r] = Bv[pb]; ri[r] = BI[pb]; pb++; }
            }
            sd[t][0] = rd[0]; sd[t][1] = rd[1]; sd[t][2] = rd[2];
            si[t][0] = ri[0]; si[t][1] = ri[1]; si[t][2] = ri[2];
        }
        __syncthreads();
    }

    __shared__ float wsh[3];
    __shared__ int   ish[3];
    __shared__ float agg[CT + 1];

    if (t == 0) {
        float w[3];
        #pragma unroll
        for (int k = 0; k < 3; k++) {
            int i = si[0][k];
            ish[k] = i;
            // weights use the DIRECT distance form, like reference _gaussian_interpolation
            float dx = __fsub_rn(Pb[i],          qx);
            float dy = __fsub_rn(Pb[NN + i],     qy);
            float dz = __fsub_rn(Pb[2 * NN + i], qz);
            float ds = __fadd_rn(__fadd_rn(__fmul_rn(dx, dx), __fmul_rn(dy, dy)),
                                 __fmul_rn(dz, dz));
            w[k] = expf(-0.5f * ds);
        }
        float Z = __fadd_rn(__fadd_rn(w[0], w[1]), w[2]);
        wsh[0] = w[0] / Z; wsh[1] = w[1] / Z; wsh[2] = w[2] / Z;
    }
    __syncthreads();

    const int   i0 = ish[0], i1 = ish[1], i2 = ish[2];
    const float w0 = wsh[0], w1 = wsh[1], w2 = wsh[2];

    if (t < 3) agg[t] = (t == 0) ? qx : ((t == 1) ? qy : qz);

    // interpolated features: channels 0..383 -> agg[3+c]
    for (int c = t; c < C1 + C2; c += 256) {
        const float* base = (c < C1)
            ? (F1 + ((size_t)b * C1 + c) * NN)
            : (F2 + ((size_t)b * C2 + (c - C1)) * NN);
        float f0 = base[i0], f1 = base[i1], f2 = base[i2];
        float v = __fadd_rn(__fadd_rn(__fmul_rn(f0, w0), __fmul_rn(f1, w1)),
                            __fmul_rn(f2, w2));
        agg[3 + c] = v;
    }
    // global feats: agg[387..1410]
    for (int c = t; c < CG; c += 256) {
        agg[3 + C1 + C2 + c] = G[(size_t)b * CG + c];
    }
    __syncthreads();

    // adaptive max pool 1411 -> 4096 over the agg row; window len is 1 or 2
    float* orow = out + ((size_t)b * MM + m) * MM;
    for (int j = t; j < MM; j += 256) {
        int s = (j * CT) >> 12;                  // floor(j*1411/4096)
        int e = ((j + 1) * CT + (MM - 1)) >> 12; // ceil((j+1)*1411/4096)
        float v = agg[s];
        if (e - s > 1) v = fmaxf(v, agg[s + 1]);
        orow[j] = v;
    }
}

extern "C" void kernel_launch(void* const* d_in, const int* in_sizes, int n_in,
                              void* d_out, int out_size, void* d_ws, size_t ws_size,
                              hipStream_t stream) {
    (void)in_sizes; (void)n_in; (void)out_size; (void)d_ws; (void)ws_size;
    const float* P  = (const float*)d_in[0];
    const float* Q  = (const float*)d_in[1];
    const float* F1 = (const float*)d_in[2];
    const float* F2 = (const float*)d_in[3];
    const float* G  = (const float*)d_in[4];
    float* out = (float*)d_out;

    dim3 grid(BB * MM);
    dim3 block(256);
    hipLaunchKernelGGL(p2p_fused, grid, block, 0, stream, P, Q, F1, F2, G, out);
}

// Round 2
// 164.210 us; speedup vs baseline: 1.7412x; 1.7412x over previous
//
#include <hip/hip_runtime.h>

#define BB 2
#define NN 16384
#define MM 4096
#define C1 128
#define C2 256
#define CF 384    // C1+C2
#define CG 1024
#define CT 1411   // 3 + 384 + 1024
#define FLTMAX 3.402823466e+38f

// ---------------- fallback (round-1) kernel ----------------
__global__ __launch_bounds__(256) void p2p_fused(
    const float* __restrict__ P, const float* __restrict__ Q,
    const float* __restrict__ F1, const float* __restrict__ F2,
    const float* __restrict__ G, float* __restrict__ out)
{
    const int t  = threadIdx.x;
    const int bm = blockIdx.x;
    const int b  = bm >> 12;
    const int m  = bm & (MM - 1);

    const float* Pb = P + (size_t)b * 3 * NN;
    const float qx = Q[(size_t)b * 3 * MM + 0 * MM + m];
    const float qy = Q[(size_t)b * 3 * MM + 1 * MM + m];
    const float qz = Q[(size_t)b * 3 * MM + 2 * MM + m];
    const float q2 = __fadd_rn(__fadd_rn(__fmul_rn(qx, qx), __fmul_rn(qy, qy)),
                               __fmul_rn(qz, qz));

    float bd0 = FLTMAX, bd1 = FLTMAX, bd2 = FLTMAX;
    int   bi0 = 0x7fffffff, bi1 = 0x7fffffff, bi2 = 0x7fffffff;

    for (int n = t; n < NN; n += 256) {
        float px = Pb[n];
        float py = Pb[NN + n];
        float pz = Pb[2 * NN + n];
        float p2 = __fadd_rn(__fadd_rn(__fmul_rn(px, px), __fmul_rn(py, py)),
                             __fmul_rn(pz, pz));
        float qp = __fadd_rn(__fadd_rn(__fmul_rn(qx, px), __fmul_rn(qy, py)),
                             __fmul_rn(qz, pz));
        float d2 = __fsub_rn(__fadd_rn(q2, p2), __fadd_rn(qp, qp));
        if (d2 < bd2) {
            if (d2 < bd1) {
                if (d2 < bd0) { bd2 = bd1; bi2 = bi1; bd1 = bd0; bi1 = bi0; bd0 = d2; bi0 = n; }
                else          { bd2 = bd1; bi2 = bi1; bd1 = d2;  bi1 = n; }
            } else            { bd2 = d2;  bi2 = n; }
        }
    }

    __shared__ float sd[256][3];
    __shared__ int   si[256][3];
    sd[t][0] = bd0; sd[t][1] = bd1; sd[t][2] = bd2;
    si[t][0] = bi0; si[t][1] = bi1; si[t][2] = bi2;
    __syncthreads();

    for (int off = 128; off >= 1; off >>= 1) {
        if (t < off) {
            float A[3]  = { sd[t][0], sd[t][1], sd[t][2] };
            int   AI[3] = { si[t][0], si[t][1], si[t][2] };
            float Bv[3] = { sd[t + off][0], sd[t + off][1], sd[t + off][2] };
            int   BI[3] = { si[t + off][0], si[t + off][1], si[t + off][2] };
            float rd[3]; int ri[3];
            int pa = 0, pb = 0;
            #pragma unroll
            for (int r = 0; r < 3; r++) {
                bool ta = (A[pa] < Bv[pb]) || (A[pa] == Bv[pb] && AI[pa] < BI[pb]);
                if (ta) { rd[r] = A[pa];  ri[r] = AI[pa]; pa++; }
                else    { rd[r] = Bv[pb]; ri[r] = BI[pb]; pb++; }
            }
            sd[t][0] = rd[0]; sd[t][1] = rd[1]; sd[t][2] = rd[2];
            si[t][0] = ri[0]; si[t][1] = ri[1]; si[t][2] = ri[2];
        }
        __syncthreads();
    }

    __shared__ float wsh[3];
    __shared__ int   ish[3];
    __shared__ float agg[CT + 1];

    if (t == 0) {
        float w[3];
        #pragma unroll
        for (int k = 0; k < 3; k++) {
            int i = si[0][k];
            ish[k] = i;
            float dx = __fsub_rn(Pb[i],          qx);
            float dy = __fsub_rn(Pb[NN + i],     qy);
            float dz = __fsub_rn(Pb[2 * NN + i], qz);
            float ds = __fadd_rn(__fadd_rn(__fmul_rn(dx, dx), __fmul_rn(dy, dy)),
                                 __fmul_rn(dz, dz));
            w[k] = expf(-0.5f * ds);
        }
        float Z = __fadd_rn(__fadd_rn(w[0], w[1]), w[2]);
        wsh[0] = w[0] / Z; wsh[1] = w[1] / Z; wsh[2] = w[2] / Z;
    }
    __syncthreads();

    const int   i0 = ish[0], i1 = ish[1], i2 = ish[2];
    const float w0 = wsh[0], w1 = wsh[1], w2 = wsh[2];

    if (t < 3) agg[t] = (t == 0) ? qx : ((t == 1) ? qy : qz);

    for (int c = t; c < C1 + C2; c += 256) {
        const float* base = (c < C1)
            ? (F1 + ((size_t)b * C1 + c) * NN)
            : (F2 + ((size_t)b * C2 + (c - C1)) * NN);
        float f0 = base[i0], f1 = base[i1], f2 = base[i2];
        float v = __fadd_rn(__fadd_rn(__fmul_rn(f0, w0), __fmul_rn(f1, w1)),
                            __fmul_rn(f2, w2));
        agg[3 + c] = v;
    }
    for (int c = t; c < CG; c += 256) {
        agg[3 + C1 + C2 + c] = G[(size_t)b * CG + c];
    }
    __syncthreads();

    float* orow = out + ((size_t)b * MM + m) * MM;
    for (int j = t; j < MM; j += 256) {
        int s = (j * CT) >> 12;
        int e = ((j + 1) * CT + (MM - 1)) >> 12;
        float v = agg[s];
        if (e - s > 1) v = fmaxf(v, agg[s + 1]);
        orow[j] = v;
    }
}

// ---------------- kernel 1: transpose feats to Ft[b][n][384] ----------------
__global__ __launch_bounds__(256) void transpose_feats(
    const float* __restrict__ F1, const float* __restrict__ F2,
    float* __restrict__ Ft)
{
    __shared__ float tile[64][65];
    const int blk = blockIdx.x;           // 0..3071
    const int b  = blk / 1536;
    const int r  = blk % 1536;
    const int ct = r / 256;               // 0..5
    const int nt = r % 256;               // 0..255
    const int c0 = ct * 64, n0 = nt * 64;
    const int tx = threadIdx.x & 63;
    const int ty = threadIdx.x >> 6;      // 0..3

    #pragma unroll 4
    for (int i = 0; i < 16; i++) {
        int cl = ty + i * 4;
        int c  = c0 + cl;
        const float* src = (c < C1)
            ? (F1 + ((size_t)b * C1 + c) * NN)
            : (F2 + ((size_t)b * C2 + (c - C1)) * NN);
        tile[cl][tx] = src[n0 + tx];
    }
    __syncthreads();
    #pragma unroll 4
    for (int i = 0; i < 16; i++) {
        int nl = ty + i * 4;
        Ft[((size_t)b * NN + (n0 + nl)) * CF + c0 + tx] = tile[tx][nl];
    }
}

// ---------------- kernel 2: kNN + weights -> rec[b*M+m][8] ----------------
#define KQB 16     // queries per block
#define KTP 2048   // points per LDS tile
__global__ __launch_bounds__(256) void knn_kernel(
    const float* __restrict__ P, const float* __restrict__ Q,
    float* __restrict__ rec)
{
    // pts: point p at float index p*4 + ((p>>7)<<2) (16B pad per 128 pts -> bank spread)
    __shared__ float pts[KTP * 4 + 64];
    __shared__ float md[256 * 3];
    __shared__ int   mi[256 * 3];

    const int t   = threadIdx.x;
    const int q   = t & 15;
    const int rep = t >> 4;               // 0..15
    const int mg  = blockIdx.x * KQB + q;
    const int b   = mg >> 12;
    const int m   = mg & (MM - 1);

    const float* Pb = P + (size_t)b * 3 * NN;
    const float qx = Q[(size_t)b * 3 * MM + m];
    const float qy = Q[(size_t)b * 3 * MM + MM + m];
    const float qz = Q[(size_t)b * 3 * MM + 2 * MM + m];
    const float q2 = __fadd_rn(__fadd_rn(__fmul_rn(qx, qx), __fmul_rn(qy, qy)),
                               __fmul_rn(qz, qz));

    float bd0 = FLTMAX, bd1 = FLTMAX, bd2 = FLTMAX;
    int   bi0 = 0x7fffffff, bi1 = 0x7fffffff, bi2 = 0x7fffffff;

    for (int T = 0; T < NN / KTP; T++) {
        __syncthreads();
        #pragma unroll
        for (int s = 0; s < KTP / 256; s++) {
            int p = s * 256 + t;
            int n = T * KTP + p;
            float x = Pb[n], y = Pb[NN + n], z = Pb[2 * NN + n];
            float p2 = __fadd_rn(__fadd_rn(__fmul_rn(x, x), __fmul_rn(y, y)),
                                 __fmul_rn(z, z));
            int a = p * 4 + ((p >> 7) << 2);
            pts[a] = x; pts[a + 1] = y; pts[a + 2] = z; pts[a + 3] = p2;
        }
        __syncthreads();

        const int abase = rep * 512 + (rep << 2);
        const int nbase = T * KTP + rep * 128;
        #pragma unroll 4
        for (int i = 0; i < 128; i++) {
            float4 v = *(const float4*)&pts[abase + i * 4];
            float qp = __fadd_rn(__fadd_rn(__fmul_rn(qx, v.x), __fmul_rn(qy, v.y)),
                                 __fmul_rn(qz, v.z));
            float d2 = __fsub_rn(__fadd_rn(q2, v.w), __fadd_rn(qp, qp));
            if (d2 < bd2) {
                int n = nbase + i;
                if (d2 < bd1) {
                    if (d2 < bd0) { bd2 = bd1; bi2 = bi1; bd1 = bd0; bi1 = bi0; bd0 = d2; bi0 = n; }
                    else          { bd2 = bd1; bi2 = bi1; bd1 = d2;  bi1 = n; }
                } else            { bd2 = d2;  bi2 = n; }
            }
        }
    }

    md[t * 3 + 0] = bd0; md[t * 3 + 1] = bd1; md[t * 3 + 2] = bd2;
    mi[t * 3 + 0] = bi0; mi[t * 3 + 1] = bi1; mi[t * 3 + 2] = bi2;
    __syncthreads();

    if (t < KQB) {
        float rd0 = FLTMAX, rd1 = FLTMAX, rd2v = FLTMAX;
        int   ri0 = 0x7fffffff, ri1 = 0x7fffffff, ri2 = 0x7fffffff;
        for (int r2 = 0; r2 < 16; r2++) {
            int base = (r2 * 16 + t) * 3;
            #pragma unroll
            for (int k = 0; k < 3; k++) {
                float d = md[base + k];
                int   ii = mi[base + k];
                bool b2 = (d < rd2v) || (d == rd2v && ii < ri2);
                if (b2) {
                    bool b1 = (d < rd1) || (d == rd1 && ii < ri1);
                    if (b1) {
                        bool b0 = (d < rd0) || (d == rd0 && ii < ri0);
                        if (b0) { rd2v = rd1; ri2 = ri1; rd1 = rd0; ri1 = ri0; rd0 = d; ri0 = ii; }
                        else    { rd2v = rd1; ri2 = ri1; rd1 = d;   ri1 = ii; }
                    } else      { rd2v = d;   ri2 = ii; }
                }
            }
        }
        // weights: direct distance form
        float w[3]; int ids[3] = { ri0, ri1, ri2 };
        #pragma unroll
        for (int k = 0; k < 3; k++) {
            int i = ids[k];
            float dx = __fsub_rn(Pb[i],          qx);
            float dy = __fsub_rn(Pb[NN + i],     qy);
            float dz = __fsub_rn(Pb[2 * NN + i], qz);
            float ds = __fadd_rn(__fadd_rn(__fmul_rn(dx, dx), __fmul_rn(dy, dy)),
                                 __fmul_rn(dz, dz));
            w[k] = expf(-0.5f * ds);
        }
        float Z = __fadd_rn(__fadd_rn(w[0], w[1]), w[2]);
        float* R = rec + (size_t)mg * 8;
        R[0] = __int_as_float(ri0);
        R[1] = __int_as_float(ri1);
        R[2] = __int_as_float(ri2);
        R[3] = w[0] / Z;
        R[4] = w[1] / Z;
        R[5] = w[2] / Z;
    }
}

// ---------------- kernel 3: pooled-global row per batch (j>=1124) ----------------
__global__ __launch_bounds__(256) void pg_kernel(
    const float* __restrict__ G, float* __restrict__ pg)
{
    int gid = blockIdx.x * 256 + threadIdx.x;
    int b   = gid / 2972;
    int jj  = gid % 2972;
    if (b >= BB) return;
    int j = 1124 + jj;
    int s = (j * CT) >> 12;
    int e = ((j + 1) * CT + (MM - 1)) >> 12;
    float v = G[(size_t)b * CG + (s - 387)];
    if (e - s > 1) v = fmaxf(v, G[(size_t)b * CG + (s - 386)]);
    pg[(size_t)b * MM + j] = v;
}

// ---------------- kernel 4: gather + interp + pool + write ----------------
__global__ __launch_bounds__(256) void interp_pool(
    const float* __restrict__ Q, const float* __restrict__ G,
    const float* __restrict__ Ft, const float* __restrict__ rec,
    const float* __restrict__ pg, float* __restrict__ out)
{
    __shared__ float agg[392];
    __shared__ float srec[8];
    const int t  = threadIdx.x;
    const int mg = blockIdx.x;
    const int b  = mg >> 12;
    const int m  = mg & (MM - 1);

    if (t < 8) srec[t] = rec[(size_t)mg * 8 + t];
    if (t == 8) agg[387] = G[(size_t)b * CG];
    if (t < 3) agg[t] = Q[(size_t)b * 3 * MM + t * MM + m];
    __syncthreads();

    const int i0 = __float_as_int(srec[0]);
    const int i1 = __float_as_int(srec[1]);
    const int i2 = __float_as_int(srec[2]);
    const float w0 = srec[3], w1 = srec[4], w2 = srec[5];
    const float* r0 = Ft + ((size_t)b * NN + i0) * CF;
    const float* r1 = Ft + ((size_t)b * NN + i1) * CF;
    const float* r2 = Ft + ((size_t)b * NN + i2) * CF;

    for (int c = t; c < CF; c += 256) {
        float v = __fadd_rn(__fadd_rn(__fmul_rn(r0[c], w0), __fmul_rn(r1[c], w1)),
                            __fmul_rn(r2[c], w2));
        agg[3 + c] = v;
    }
    __syncthreads();

    float4* out4 = (float4*)(out + (size_t)mg * MM);
    for (int g = t; g < 281; g += 256) {
        int j0 = g * 4;
        float4 o;
        float* op = &o.x;
        #pragma unroll
        for (int u = 0; u < 4; u++) {
            int j = j0 + u;
            int s = (j * CT) >> 12;
            int e = ((j + 1) * CT + (MM - 1)) >> 12;
            float v = agg[s];
            if (e - s > 1) v = fmaxf(v, agg[s + 1]);
            op[u] = v;
        }
        out4[g] = o;
    }
    const float4* pg4 = (const float4*)(pg + (size_t)b * MM);
    for (int g = t; g < 743; g += 256) {
        out4[281 + g] = pg4[281 + g];
    }
}

extern "C" void kernel_launch(void* const* d_in, const int* in_sizes, int n_in,
                              void* d_out, int out_size, void* d_ws, size_t ws_size,
                              hipStream_t stream) {
    (void)in_sizes; (void)n_in; (void)out_size;
    const float* P  = (const float*)d_in[0];
    const float* Q  = (const float*)d_in[1];
    const float* F1 = (const float*)d_in[2];
    const float* F2 = (const float*)d_in[3];
    const float* G  = (const float*)d_in[4];
    float* out = (float*)d_out;

    const size_t off_ft  = 0;
    const size_t sz_ft   = (size_t)BB * NN * CF * 4;        // 50,331,648
    const size_t off_pg  = off_ft + sz_ft;
    const size_t sz_pg   = (size_t)BB * MM * 4;             // 32,768
    const size_t off_rec = off_pg + sz_pg;
    const size_t sz_rec  = (size_t)BB * MM * 8 * 4;         // 262,144
    const size_t need    = off_rec + sz_rec;

    if (ws_size >= need) {
        float* Ft  = (float*)((char*)d_ws + off_ft);
        float* pg  = (float*)((char*)d_ws + off_pg);
        float* rec = (float*)((char*)d_ws + off_rec);

        hipLaunchKernelGGL(knn_kernel, dim3(BB * MM / KQB), dim3(256), 0, stream, P, Q, rec);
        hipLaunchKernelGGL(transpose_feats, dim3(BB * (NN / 64) * (CF / 64)), dim3(256), 0, stream, F1, F2, Ft);
        hipLaunchKernelGGL(pg_kernel, dim3((BB * 2972 + 255) / 256), dim3(256), 0, stream, G, pg);
        hipLaunchKernelGGL(interp_pool, dim3(BB * MM), dim3(256), 0, stream, Q, G, Ft, rec, pg, out);
    } else {
        hipLaunchKernelGGL(p2p_fused, dim3(BB * MM), dim3(256), 0, stream, P, Q, F1, F2, G, out);
    }
}

// Round 3
// 157.116 us; speedup vs baseline: 1.8198x; 1.0451x over previous
//
#include <hip/hip_runtime.h>

#define BB 2
#define NN 16384
#define MM 4096
#define C1 128
#define C2 256
#define CF 384    // C1+C2
#define CG 1024
#define CT 1411   // 3 + 384 + 1024
#define FLTMAX 3.402823466e+38f
#define SPLIT 32            // point-splits per query
#define PTS_PER (NN / SPLIT) // 512 points per wave-scan

// ---------------- fallback (round-1) kernel ----------------
__global__ __launch_bounds__(256) void p2p_fused(
    const float* __restrict__ P, const float* __restrict__ Q,
    const float* __restrict__ F1, const float* __restrict__ F2,
    const float* __restrict__ G, float* __restrict__ out)
{
    const int t  = threadIdx.x;
    const int bm = blockIdx.x;
    const int b  = bm >> 12;
    const int m  = bm & (MM - 1);

    const float* Pb = P + (size_t)b * 3 * NN;
    const float qx = Q[(size_t)b * 3 * MM + 0 * MM + m];
    const float qy = Q[(size_t)b * 3 * MM + 1 * MM + m];
    const float qz = Q[(size_t)b * 3 * MM + 2 * MM + m];
    const float q2 = __fadd_rn(__fadd_rn(__fmul_rn(qx, qx), __fmul_rn(qy, qy)),
                               __fmul_rn(qz, qz));

    float bd0 = FLTMAX, bd1 = FLTMAX, bd2 = FLTMAX;
    int   bi0 = 0x7fffffff, bi1 = 0x7fffffff, bi2 = 0x7fffffff;

    for (int n = t; n < NN; n += 256) {
        float px = Pb[n];
        float py = Pb[NN + n];
        float pz = Pb[2 * NN + n];
        float p2 = __fadd_rn(__fadd_rn(__fmul_rn(px, px), __fmul_rn(py, py)),
                             __fmul_rn(pz, pz));
        float qp = __fadd_rn(__fadd_rn(__fmul_rn(qx, px), __fmul_rn(qy, py)),
                             __fmul_rn(qz, pz));
        float d2 = __fsub_rn(__fadd_rn(q2, p2), __fadd_rn(qp, qp));
        if (d2 < bd2) {
            if (d2 < bd1) {
                if (d2 < bd0) { bd2 = bd1; bi2 = bi1; bd1 = bd0; bi1 = bi0; bd0 = d2; bi0 = n; }
                else          { bd2 = bd1; bi2 = bi1; bd1 = d2;  bi1 = n; }
            } else            { bd2 = d2;  bi2 = n; }
        }
    }

    __shared__ float sd[256][3];
    __shared__ int   si[256][3];
    sd[t][0] = bd0; sd[t][1] = bd1; sd[t][2] = bd2;
    si[t][0] = bi0; si[t][1] = bi1; si[t][2] = bi2;
    __syncthreads();

    for (int off = 128; off >= 1; off >>= 1) {
        if (t < off) {
            float A[3]  = { sd[t][0], sd[t][1], sd[t][2] };
            int   AI[3] = { si[t][0], si[t][1], si[t][2] };
            float Bv[3] = { sd[t + off][0], sd[t + off][1], sd[t + off][2] };
            int   BI[3] = { si[t + off][0], si[t + off][1], si[t + off][2] };
            float rd[3]; int ri[3];
            int pa = 0, pb = 0;
            #pragma unroll
            for (int r = 0; r < 3; r++) {
                bool ta = (A[pa] < Bv[pb]) || (A[pa] == Bv[pb] && AI[pa] < BI[pb]);
                if (ta) { rd[r] = A[pa];  ri[r] = AI[pa]; pa++; }
                else    { rd[r] = Bv[pb]; ri[r] = BI[pb]; pb++; }
            }
            sd[t][0] = rd[0]; sd[t][1] = rd[1]; sd[t][2] = rd[2];
            si[t][0] = ri[0]; si[t][1] = ri[1]; si[t][2] = ri[2];
        }
        __syncthreads();
    }

    __shared__ float wsh[3];
    __shared__ int   ish[3];
    __shared__ float agg[CT + 1];

    if (t == 0) {
        float w[3];
        #pragma unroll
        for (int k = 0; k < 3; k++) {
            int i = si[0][k];
            ish[k] = i;
            float dx = __fsub_rn(Pb[i],          qx);
            float dy = __fsub_rn(Pb[NN + i],     qy);
            float dz = __fsub_rn(Pb[2 * NN + i], qz);
            float ds = __fadd_rn(__fadd_rn(__fmul_rn(dx, dx), __fmul_rn(dy, dy)),
                                 __fmul_rn(dz, dz));
            w[k] = expf(-0.5f * ds);
        }
        float Z = __fadd_rn(__fadd_rn(w[0], w[1]), w[2]);
        wsh[0] = w[0] / Z; wsh[1] = w[1] / Z; wsh[2] = w[2] / Z;
    }
    __syncthreads();

    const int   i0 = ish[0], i1 = ish[1], i2 = ish[2];
    const float w0 = wsh[0], w1 = wsh[1], w2 = wsh[2];

    if (t < 3) agg[t] = (t == 0) ? qx : ((t == 1) ? qy : qz);

    for (int c = t; c < C1 + C2; c += 256) {
        const float* base = (c < C1)
            ? (F1 + ((size_t)b * C1 + c) * NN)
            : (F2 + ((size_t)b * C2 + (c - C1)) * NN);
        float f0 = base[i0], f1 = base[i1], f2 = base[i2];
        float v = __fadd_rn(__fadd_rn(__fmul_rn(f0, w0), __fmul_rn(f1, w1)),
                            __fmul_rn(f2, w2));
        agg[3 + c] = v;
    }
    for (int c = t; c < CG; c += 256) {
        agg[3 + C1 + C2 + c] = G[(size_t)b * CG + c];
    }
    __syncthreads();

    float* orow = out + ((size_t)b * MM + m) * MM;
    for (int j = t; j < MM; j += 256) {
        int s = (j * CT) >> 12;
        int e = ((j + 1) * CT + (MM - 1)) >> 12;
        float v = agg[s];
        if (e - s > 1) v = fmaxf(v, agg[s + 1]);
        orow[j] = v;
    }
}

// ---------------- kernel 0: pack P4 = (x,y,z,p2) ----------------
__global__ __launch_bounds__(256) void prep_p4(
    const float* __restrict__ P, float4* __restrict__ P4)
{
    int gid = blockIdx.x * 256 + threadIdx.x;   // 0 .. BB*NN-1
    int b   = gid >> 14;                        // NN = 2^14
    int n   = gid & (NN - 1);
    const float* Pb = P + (size_t)b * 3 * NN;
    float x = Pb[n], y = Pb[NN + n], z = Pb[2 * NN + n];
    float p2 = __fadd_rn(__fadd_rn(__fmul_rn(x, x), __fmul_rn(y, y)),
                         __fmul_rn(z, z));
    P4[gid] = make_float4(x, y, z, p2);
}

// ---------------- kernel 1: kNN scan, query-per-lane, wave-uniform points ----
// grid: 1024 blocks x 256. block = (qg 0..127, ps 0..7); wave wv 0..3.
// split id sp = ps*4+wv scans points [sp*512, sp*512+512) for 64 queries.
__global__ __launch_bounds__(256) void knn_scan(
    const float4* __restrict__ P4, const float* __restrict__ Q,
    float4* __restrict__ pd, int4* __restrict__ pi)
{
    const int t    = threadIdx.x;
    const int lane = t & 63;
    const int wv   = __builtin_amdgcn_readfirstlane(t >> 6);
    const int qg   = blockIdx.x & 127;
    const int ps   = blockIdx.x >> 7;
    const int sp   = ps * 4 + wv;
    const int mg   = qg * 64 + lane;
    const int b    = qg >> 6;
    const int m    = mg & (MM - 1);

    const float qx = Q[(size_t)b * 3 * MM + m];
    const float qy = Q[(size_t)b * 3 * MM + MM + m];
    const float qz = Q[(size_t)b * 3 * MM + 2 * MM + m];
    const float q2 = __fadd_rn(__fadd_rn(__fmul_rn(qx, qx), __fmul_rn(qy, qy)),
                               __fmul_rn(qz, qz));

    const float4* Pw = P4 + b * NN + sp * PTS_PER;  // wave-uniform base
    const int nbase = sp * PTS_PER;

    float bd0 = FLTMAX, bd1 = FLTMAX, bd2 = FLTMAX;
    int   bi0 = 0x7fffffff, bi1 = 0x7fffffff, bi2 = 0x7fffffff;

    #pragma unroll 4
    for (int i = 0; i < PTS_PER; i++) {
        float4 v = Pw[i];   // uniform address -> scalar/broadcast load
        float qp = __fadd_rn(__fadd_rn(__fmul_rn(qx, v.x), __fmul_rn(qy, v.y)),
                             __fmul_rn(qz, v.z));
        float d2 = __fsub_rn(__fadd_rn(q2, v.w), __fadd_rn(qp, qp));
        if (d2 < bd2) {
            int n = nbase + i;
            if (d2 < bd1) {
                if (d2 < bd0) { bd2 = bd1; bi2 = bi1; bd1 = bd0; bi1 = bi0; bd0 = d2; bi0 = n; }
                else          { bd2 = bd1; bi2 = bi1; bd1 = d2;  bi1 = n; }
            } else            { bd2 = d2;  bi2 = n; }
        }
    }

    int o = sp * (BB * MM) + mg;
    pd[o] = make_float4(bd0, bd1, bd2, 0.0f);
    pi[o] = make_int4(bi0, bi1, bi2, 0);
}

// ---------------- kernel 2: merge partials + weights -> rec ----------------
__global__ __launch_bounds__(256) void knn_merge(
    const float4* __restrict__ P4, const float* __restrict__ Q,
    const float4* __restrict__ pd, const int4* __restrict__ pi,
    float* __restrict__ rec)
{
    const int mg = blockIdx.x * 256 + threadIdx.x;  // 32 blocks
    const int b  = mg >> 12;
    const int m  = mg & (MM - 1);

    float rd0 = FLTMAX, rd1 = FLTMAX, rd2 = FLTMAX;
    int   ri0 = 0x7fffffff, ri1 = 0x7fffffff, ri2 = 0x7fffffff;

    for (int sp = 0; sp < SPLIT; sp++) {
        float4 d4 = pd[sp * (BB * MM) + mg];
        int4   i4 = pi[sp * (BB * MM) + mg];
        float dv[3] = { d4.x, d4.y, d4.z };
        int   iv[3] = { i4.x, i4.y, i4.z };
        #pragma unroll
        for (int k = 0; k < 3; k++) {
            float d  = dv[k];
            int   ii = iv[k];
            bool b2 = (d < rd2) || (d == rd2 && ii < ri2);
            if (b2) {
                bool b1 = (d < rd1) || (d == rd1 && ii < ri1);
                if (b1) {
                    bool b0 = (d < rd0) || (d == rd0 && ii < ri0);
                    if (b0) { rd2 = rd1; ri2 = ri1; rd1 = rd0; ri1 = ri0; rd0 = d; ri0 = ii; }
                    else    { rd2 = rd1; ri2 = ri1; rd1 = d;   ri1 = ii; }
                } else      { rd2 = d;   ri2 = ii; }
            }
        }
    }

    const float qx = Q[(size_t)b * 3 * MM + m];
    const float qy = Q[(size_t)b * 3 * MM + MM + m];
    const float qz = Q[(size_t)b * 3 * MM + 2 * MM + m];

    float w[3]; int ids[3] = { ri0, ri1, ri2 };
    #pragma unroll
    for (int k = 0; k < 3; k++) {
        float4 pv = P4[b * NN + ids[k]];
        float dx = __fsub_rn(pv.x, qx);
        float dy = __fsub_rn(pv.y, qy);
        float dz = __fsub_rn(pv.z, qz);
        float ds = __fadd_rn(__fadd_rn(__fmul_rn(dx, dx), __fmul_rn(dy, dy)),
                             __fmul_rn(dz, dz));
        w[k] = expf(-0.5f * ds);
    }
    float Z = __fadd_rn(__fadd_rn(w[0], w[1]), w[2]);
    float* R = rec + (size_t)mg * 8;
    R[0] = __int_as_float(ri0);
    R[1] = __int_as_float(ri1);
    R[2] = __int_as_float(ri2);
    R[3] = w[0] / Z;
    R[4] = w[1] / Z;
    R[5] = w[2] / Z;
}

// ---------------- kernel 3: transpose feats to Ft[b][n][384] ----------------
__global__ __launch_bounds__(256) void transpose_feats(
    const float* __restrict__ F1, const float* __restrict__ F2,
    float* __restrict__ Ft)
{
    __shared__ float tile[64][65];
    const int blk = blockIdx.x;           // 0..3071
    const int b  = blk / 1536;
    const int r  = blk % 1536;
    const int ct = r / 256;               // 0..5
    const int nt = r % 256;               // 0..255
    const int c0 = ct * 64, n0 = nt * 64;
    const int tx = threadIdx.x & 63;
    const int ty = threadIdx.x >> 6;      // 0..3

    #pragma unroll 4
    for (int i = 0; i < 16; i++) {
        int cl = ty + i * 4;
        int c  = c0 + cl;
        const float* src = (c < C1)
            ? (F1 + ((size_t)b * C1 + c) * NN)
            : (F2 + ((size_t)b * C2 + (c - C1)) * NN);
        tile[cl][tx] = src[n0 + tx];
    }
    __syncthreads();
    #pragma unroll 4
    for (int i = 0; i < 16; i++) {
        int nl = ty + i * 4;
        Ft[((size_t)b * NN + (n0 + nl)) * CF + c0 + tx] = tile[tx][nl];
    }
}

// ---------------- kernel 4: pooled-global row per batch (j>=1124) ----------------
__global__ __launch_bounds__(256) void pg_kernel(
    const float* __restrict__ G, float* __restrict__ pg)
{
    int gid = blockIdx.x * 256 + threadIdx.x;
    int b   = gid / 2972;
    int jj  = gid % 2972;
    if (b >= BB) return;
    int j = 1124 + jj;
    int s = (j * CT) >> 12;
    int e = ((j + 1) * CT + (MM - 1)) >> 12;
    float v = G[(size_t)b * CG + (s - 387)];
    if (e - s > 1) v = fmaxf(v, G[(size_t)b * CG + (s - 386)]);
    pg[(size_t)b * MM + j] = v;
}

// ---------------- kernel 5: gather + interp + pool + write ----------------
__global__ __launch_bounds__(256) void interp_pool(
    const float* __restrict__ Q, const float* __restrict__ G,
    const float* __restrict__ Ft, const float* __restrict__ rec,
    const float* __restrict__ pg, float* __restrict__ out)
{
    __shared__ float agg[392];
    __shared__ float srec[8];
    const int t  = threadIdx.x;
    const int mg = blockIdx.x;
    const int b  = mg >> 12;
    const int m  = mg & (MM - 1);

    if (t < 8) srec[t] = rec[(size_t)mg * 8 + t];
    if (t == 8) agg[387] = G[(size_t)b * CG];
    if (t < 3) agg[t] = Q[(size_t)b * 3 * MM + t * MM + m];
    __syncthreads();

    const int i0 = __float_as_int(srec[0]);
    const int i1 = __float_as_int(srec[1]);
    const int i2 = __float_as_int(srec[2]);
    const float w0 = srec[3], w1 = srec[4], w2 = srec[5];
    const float* r0 = Ft + ((size_t)b * NN + i0) * CF;
    const float* r1 = Ft + ((size_t)b * NN + i1) * CF;
    const float* r2 = Ft + ((size_t)b * NN + i2) * CF;

    for (int c = t; c < CF; c += 256) {
        float v = __fadd_rn(__fadd_rn(__fmul_rn(r0[c], w0), __fmul_rn(r1[c], w1)),
                            __fmul_rn(r2[c], w2));
        agg[3 + c] = v;
    }
    __syncthreads();

    float4* out4 = (float4*)(out + (size_t)mg * MM);
    for (int g = t; g < 281; g += 256) {
        int j0 = g * 4;
        float4 o;
        float* op = &o.x;
        #pragma unroll
        for (int u = 0; u < 4; u++) {
            int j = j0 + u;
            int s = (j * CT) >> 12;
            int e = ((j + 1) * CT + (MM - 1)) >> 12;
            float v = agg[s];
            if (e - s > 1) v = fmaxf(v, agg[s + 1]);
            op[u] = v;
        }
        out4[g] = o;
    }
    const float4* pg4 = (const float4*)(pg + (size_t)b * MM);
    for (int g = t; g < 743; g += 256) {
        out4[281 + g] = pg4[281 + g];
    }
}

extern "C" void kernel_launch(void* const* d_in, const int* in_sizes, int n_in,
                              void* d_out, int out_size, void* d_ws, size_t ws_size,
                              hipStream_t stream) {
    (void)in_sizes; (void)n_in; (void)out_size;
    const float* P  = (const float*)d_in[0];
    const float* Q  = (const float*)d_in[1];
    const float* F1 = (const float*)d_in[2];
    const float* F2 = (const float*)d_in[3];
    const float* G  = (const float*)d_in[4];
    float* out = (float*)d_out;

    // Ft occupies [0, sz_ft). P4 + partials alias INSIDE the Ft region:
    // they are dead after knn_merge, and transpose_feats (which writes Ft)
    // runs after knn_merge on the same stream.
    const size_t off_ft  = 0;
    const size_t sz_ft   = (size_t)BB * NN * CF * 4;        // 50,331,648
    const size_t off_pg  = off_ft + sz_ft;
    const size_t sz_pg   = (size_t)BB * MM * 4;             // 32,768
    const size_t off_rec = off_pg + sz_pg;
    const size_t sz_rec  = (size_t)BB * MM * 8 * 4;         // 262,144
    const size_t need    = off_rec + sz_rec;                // 50,626,560

    const size_t off_p4  = 0;                               // aliases Ft
    const size_t sz_p4   = (size_t)BB * NN * 16;            // 524,288
    const size_t off_pd  = off_p4 + sz_p4;
    const size_t sz_pd   = (size_t)SPLIT * BB * MM * 16;    // 4,194,304
    const size_t off_pi  = off_pd + sz_pd;                  // +4 MB, ends < 9 MB

    if (ws_size >= need) {
        float4* P4  = (float4*)((char*)d_ws + off_p4);
        float4* pdb = (float4*)((char*)d_ws + off_pd);
        int4*   pib = (int4*)((char*)d_ws + off_pi);
        float*  Ft  = (float*)((char*)d_ws + off_ft);
        float*  pg  = (float*)((char*)d_ws + off_pg);
        float*  rec = (float*)((char*)d_ws + off_rec);

        hipLaunchKernelGGL(prep_p4,    dim3(BB * NN / 256), dim3(256), 0, stream, P, P4);
        hipLaunchKernelGGL(knn_scan,   dim3(128 * (SPLIT / 4)), dim3(256), 0, stream, P4, Q, pdb, pib);
        hipLaunchKernelGGL(knn_merge,  dim3(BB * MM / 256), dim3(256), 0, stream, P4, Q, pdb, pib, rec);
        hipLaunchKernelGGL(transpose_feats, dim3(BB * (NN / 64) * (CF / 64)), dim3(256), 0, stream, F1, F2, Ft);
        hipLaunchKernelGGL(pg_kernel,  dim3((BB * 2972 + 255) / 256), dim3(256), 0, stream, G, pg);
        hipLaunchKernelGGL(interp_pool, dim3(BB * MM), dim3(256), 0, stream, Q, G, Ft, rec, pg, out);
    } else {
        hipLaunchKernelGGL(p2p_fused, dim3(BB * MM), dim3(256), 0, stream, P, Q, F1, F2, G, out);
    }
}

// Round 4
// 156.148 us; speedup vs baseline: 1.8311x; 1.0062x over previous
//
#include <hip/hip_runtime.h>

#define BB 2
#define NN 16384
#define MM 4096
#define C1 128
#define C2 256
#define CF 384    // C1+C2
#define CG 1024
#define CT 1411   // 3 + 384 + 1024
#define FLTMAX 3.402823466e+38f
#define SPLIT 64             // point-splits per query
#define PTS_PER (NN / SPLIT) // 256 points per wave-scan

// ---------------- fallback (round-1) kernel ----------------
__global__ __launch_bounds__(256) void p2p_fused(
    const float* __restrict__ P, const float* __restrict__ Q,
    const float* __restrict__ F1, const float* __restrict__ F2,
    const float* __restrict__ G, float* __restrict__ out)
{
    const int t  = threadIdx.x;
    const int bm = blockIdx.x;
    const int b  = bm >> 12;
    const int m  = bm & (MM - 1);

    const float* Pb = P + (size_t)b * 3 * NN;
    const float qx = Q[(size_t)b * 3 * MM + 0 * MM + m];
    const float qy = Q[(size_t)b * 3 * MM + 1 * MM + m];
    const float qz = Q[(size_t)b * 3 * MM + 2 * MM + m];
    const float q2 = __fadd_rn(__fadd_rn(__fmul_rn(qx, qx), __fmul_rn(qy, qy)),
                               __fmul_rn(qz, qz));

    float bd0 = FLTMAX, bd1 = FLTMAX, bd2 = FLTMAX;
    int   bi0 = 0x7fffffff, bi1 = 0x7fffffff, bi2 = 0x7fffffff;

    for (int n = t; n < NN; n += 256) {
        float px = Pb[n];
        float py = Pb[NN + n];
        float pz = Pb[2 * NN + n];
        float p2 = __fadd_rn(__fadd_rn(__fmul_rn(px, px), __fmul_rn(py, py)),
                             __fmul_rn(pz, pz));
        float qp = __fadd_rn(__fadd_rn(__fmul_rn(qx, px), __fmul_rn(qy, py)),
                             __fmul_rn(qz, pz));
        float d2 = __fsub_rn(__fadd_rn(q2, p2), __fadd_rn(qp, qp));
        if (d2 < bd2) {
            if (d2 < bd1) {
                if (d2 < bd0) { bd2 = bd1; bi2 = bi1; bd1 = bd0; bi1 = bi0; bd0 = d2; bi0 = n; }
                else          { bd2 = bd1; bi2 = bi1; bd1 = d2;  bi1 = n; }
            } else            { bd2 = d2;  bi2 = n; }
        }
    }

    __shared__ float sd[256][3];
    __shared__ int   si[256][3];
    sd[t][0] = bd0; sd[t][1] = bd1; sd[t][2] = bd2;
    si[t][0] = bi0; si[t][1] = bi1; si[t][2] = bi2;
    __syncthreads();

    for (int off = 128; off >= 1; off >>= 1) {
        if (t < off) {
            float A[3]  = { sd[t][0], sd[t][1], sd[t][2] };
            int   AI[3] = { si[t][0], si[t][1], si[t][2] };
            float Bv[3] = { sd[t + off][0], sd[t + off][1], sd[t + off][2] };
            int   BI[3] = { si[t + off][0], si[t + off][1], si[t + off][2] };
            float rd[3]; int ri[3];
            int pa = 0, pb = 0;
            #pragma unroll
            for (int r = 0; r < 3; r++) {
                bool ta = (A[pa] < Bv[pb]) || (A[pa] == Bv[pb] && AI[pa] < BI[pb]);
                if (ta) { rd[r] = A[pa];  ri[r] = AI[pa]; pa++; }
                else    { rd[r] = Bv[pb]; ri[r] = BI[pb]; pb++; }
            }
            sd[t][0] = rd[0]; sd[t][1] = rd[1]; sd[t][2] = rd[2];
            si[t][0] = ri[0]; si[t][1] = ri[1]; si[t][2] = ri[2];
        }
        __syncthreads();
    }

    __shared__ float wsh[3];
    __shared__ int   ish[3];
    __shared__ float agg[CT + 1];

    if (t == 0) {
        float w[3];
        #pragma unroll
        for (int k = 0; k < 3; k++) {
            int i = si[0][k];
            ish[k] = i;
            float dx = __fsub_rn(Pb[i],          qx);
            float dy = __fsub_rn(Pb[NN + i],     qy);
            float dz = __fsub_rn(Pb[2 * NN + i], qz);
            float ds = __fadd_rn(__fadd_rn(__fmul_rn(dx, dx), __fmul_rn(dy, dy)),
                                 __fmul_rn(dz, dz));
            w[k] = expf(-0.5f * ds);
        }
        float Z = __fadd_rn(__fadd_rn(w[0], w[1]), w[2]);
        wsh[0] = w[0] / Z; wsh[1] = w[1] / Z; wsh[2] = w[2] / Z;
    }
    __syncthreads();

    const int   i0 = ish[0], i1 = ish[1], i2 = ish[2];
    const float w0 = wsh[0], w1 = wsh[1], w2 = wsh[2];

    if (t < 3) agg[t] = (t == 0) ? qx : ((t == 1) ? qy : qz);

    for (int c = t; c < C1 + C2; c += 256) {
        const float* base = (c < C1)
            ? (F1 + ((size_t)b * C1 + c) * NN)
            : (F2 + ((size_t)b * C2 + (c - C1)) * NN);
        float f0 = base[i0], f1 = base[i1], f2 = base[i2];
        float v = __fadd_rn(__fadd_rn(__fmul_rn(f0, w0), __fmul_rn(f1, w1)),
                            __fmul_rn(f2, w2));
        agg[3 + c] = v;
    }
    for (int c = t; c < CG; c += 256) {
        agg[3 + C1 + C2 + c] = G[(size_t)b * CG + c];
    }
    __syncthreads();

    float* orow = out + ((size_t)b * MM + m) * MM;
    for (int j = t; j < MM; j += 256) {
        int s = (j * CT) >> 12;
        int e = ((j + 1) * CT + (MM - 1)) >> 12;
        float v = agg[s];
        if (e - s > 1) v = fmaxf(v, agg[s + 1]);
        orow[j] = v;
    }
}

// ---------------- kernel 0: pack P4 = (x,y,z,p2) ----------------
__global__ __launch_bounds__(256) void prep_p4(
    const float* __restrict__ P, float4* __restrict__ P4)
{
    int gid = blockIdx.x * 256 + threadIdx.x;   // 0 .. BB*NN-1
    int b   = gid >> 14;                        // NN = 2^14
    int n   = gid & (NN - 1);
    const float* Pb = P + (size_t)b * 3 * NN;
    float x = Pb[n], y = Pb[NN + n], z = Pb[2 * NN + n];
    float p2 = __fadd_rn(__fadd_rn(__fmul_rn(x, x), __fmul_rn(y, y)),
                         __fmul_rn(z, z));
    P4[gid] = make_float4(x, y, z, p2);
}

// exact-rn distance, identical rounding to the np reference expansion
__device__ __forceinline__ float dist_rn(float qx, float qy, float qz, float q2,
                                         float4 v)
{
    float qp = __fadd_rn(__fadd_rn(__fmul_rn(qx, v.x), __fmul_rn(qy, v.y)),
                         __fmul_rn(qz, v.z));
    return __fsub_rn(__fadd_rn(q2, v.w), __fadd_rn(qp, qp));
}

// branchless sorted insert of (dv,nv) into ascending (b0,b1,b2)/(i0,i1,i2);
// strict < keeps earlier (lower-index) entries on ties == top_k stability
#define INS(dv, nv)                                                          \
    {                                                                        \
        bool c0 = (dv) < b0, c1 = (dv) < b1, c2 = (dv) < b2;                 \
        float nb2 = c1 ? b1 : (c2 ? (dv) : b2);                              \
        int   ni2 = c1 ? i1 : (c2 ? (nv) : i2);                              \
        float nb1 = c0 ? b0 : (c1 ? (dv) : b1);                              \
        int   ni1 = c0 ? i0 : (c1 ? (nv) : i1);                              \
        float nb0 = c0 ? (dv) : b0;                                          \
        int   ni0 = c0 ? (nv) : i0;                                          \
        b0 = nb0; b1 = nb1; b2 = nb2; i0 = ni0; i1 = ni1; i2 = ni2;          \
    }

// ---------------- kernel 1: kNN scan, query-per-lane, 4-pt tournament ------
// grid: 2048 blocks x 256. block = (qg 0..127, ps 0..15); wave wv 0..3.
// split sp = ps*4+wv scans points [sp*256, sp*256+256) for 64 queries.
__global__ __launch_bounds__(256) void knn_scan(
    const float4* __restrict__ P4, const float* __restrict__ Q,
    float4* __restrict__ pd, int4* __restrict__ pi)
{
    const int t    = threadIdx.x;
    const int lane = t & 63;
    const int wv   = __builtin_amdgcn_readfirstlane(t >> 6);
    const int qg   = blockIdx.x & 127;
    const int ps   = blockIdx.x >> 7;
    const int sp   = ps * 4 + wv;
    const int mg   = qg * 64 + lane;
    const int b    = qg >> 6;
    const int m    = mg & (MM - 1);

    const float qx = Q[(size_t)b * 3 * MM + m];
    const float qy = Q[(size_t)b * 3 * MM + MM + m];
    const float qz = Q[(size_t)b * 3 * MM + 2 * MM + m];
    const float q2 = __fadd_rn(__fadd_rn(__fmul_rn(qx, qx), __fmul_rn(qy, qy)),
                               __fmul_rn(qz, qz));

    const float4* Pw = P4 + b * NN + sp * PTS_PER;  // wave-uniform base
    const int nbase = sp * PTS_PER;

    float b0 = FLTMAX, b1 = FLTMAX, b2 = FLTMAX;
    int   i0 = 0x7fffffff, i1 = 0x7fffffff, i2 = 0x7fffffff;

    #pragma unroll 2
    for (int g = 0; g < PTS_PER; g += 4) {
        float4 v0 = Pw[g + 0];
        float4 v1 = Pw[g + 1];
        float4 v2 = Pw[g + 2];
        float4 v3 = Pw[g + 3];
        float d0  = dist_rn(qx, qy, qz, q2, v0);
        float d1  = dist_rn(qx, qy, qz, q2, v1);
        float d2v = dist_rn(qx, qy, qz, q2, v2);
        float d3  = dist_rn(qx, qy, qz, q2, v3);

        // min4 with index (ties -> lower u, matching ascending-n stability)
        bool  cA = d1 < d0;   float mA = fminf(d0, d1);   int uA = cA ? 1 : 0;
        bool  cB = d3 < d2v;  float mB = fminf(d2v, d3);  int uB = cB ? 3 : 2;
        bool  cF = mB < mA;   float mF = fminf(mA, mB);   int uF = cF ? uB : uA;
        int nmin = nbase + g + uF;

        // second smallest of the 4 (for exactness fixup)
        float MA = fmaxf(d0, d1), MB = fmaxf(d2v, d3);
        float sec = fminf(cF ? mA : mB, cF ? MB : MA);

        INS(mF, nmin);

        if (sec < b2) {  // rare: group holds >=2 of the running top-3
            #pragma unroll
            for (int u = 0; u < 4; u++) {
                float du = (u == 0) ? d0 : ((u == 1) ? d1 : ((u == 2) ? d2v : d3));
                if (uF != u) {
                    INS(du, nbase + g + u);
                }
            }
        }
    }

    int o = sp * (BB * MM) + mg;
    pd[o] = make_float4(b0, b1, b2, 0.0f);
    pi[o] = make_int4(i0, i1, i2, 0);
}

// ---------------- kernel 2: merge partials + weights -> rec ----------------
__global__ __launch_bounds__(256) void knn_merge(
    const float4* __restrict__ P4, const float* __restrict__ Q,
    const float4* __restrict__ pd, const int4* __restrict__ pi,
    float* __restrict__ rec)
{
    const int mg = blockIdx.x * 256 + threadIdx.x;  // 32 blocks
    const int b  = mg >> 12;
    const int m  = mg & (MM - 1);

    float rd0 = FLTMAX, rd1 = FLTMAX, rd2 = FLTMAX;
    int   ri0 = 0x7fffffff, ri1 = 0x7fffffff, ri2 = 0x7fffffff;

    for (int sp = 0; sp < SPLIT; sp++) {
        float4 d4 = pd[sp * (BB * MM) + mg];
        int4   i4 = pi[sp * (BB * MM) + mg];
        float dv[3] = { d4.x, d4.y, d4.z };
        int   iv[3] = { i4.x, i4.y, i4.z };
        #pragma unroll
        for (int k = 0; k < 3; k++) {
            float d  = dv[k];
            int   ii = iv[k];
            bool b2c = (d < rd2) || (d == rd2 && ii < ri2);
            if (b2c) {
                bool b1c = (d < rd1) || (d == rd1 && ii < ri1);
                if (b1c) {
                    bool b0c = (d < rd0) || (d == rd0 && ii < ri0);
                    if (b0c) { rd2 = rd1; ri2 = ri1; rd1 = rd0; ri1 = ri0; rd0 = d; ri0 = ii; }
                    else     { rd2 = rd1; ri2 = ri1; rd1 = d;   ri1 = ii; }
                } else       { rd2 = d;   ri2 = ii; }
            }
        }
    }

    const float qx = Q[(size_t)b * 3 * MM + m];
    const float qy = Q[(size_t)b * 3 * MM + MM + m];
    const float qz = Q[(size_t)b * 3 * MM + 2 * MM + m];

    float w[3]; int ids[3] = { ri0, ri1, ri2 };
    #pragma unroll
    for (int k = 0; k < 3; k++) {
        float4 pv = P4[b * NN + ids[k]];
        float dx = __fsub_rn(pv.x, qx);
        float dy = __fsub_rn(pv.y, qy);
        float dz = __fsub_rn(pv.z, qz);
        float ds = __fadd_rn(__fadd_rn(__fmul_rn(dx, dx), __fmul_rn(dy, dy)),
                             __fmul_rn(dz, dz));
        w[k] = expf(-0.5f * ds);
    }
    float Z = __fadd_rn(__fadd_rn(w[0], w[1]), w[2]);
    float* R = rec + (size_t)mg * 8;
    R[0] = __int_as_float(ri0);
    R[1] = __int_as_float(ri1);
    R[2] = __int_as_float(ri2);
    R[3] = w[0] / Z;
    R[4] = w[1] / Z;
    R[5] = w[2] / Z;
}

// ---------------- kernel 3: transpose feats to Ft[b][n][384] ----------------
__global__ __launch_bounds__(256) void transpose_feats(
    const float* __restrict__ F1, const float* __restrict__ F2,
    float* __restrict__ Ft)
{
    __shared__ float tile[64][65];
    const int blk = blockIdx.x;           // 0..3071
    const int b  = blk / 1536;
    const int r  = blk % 1536;
    const int ct = r / 256;               // 0..5
    const int nt = r % 256;               // 0..255
    const int c0 = ct * 64, n0 = nt * 64;
    const int tx = threadIdx.x & 63;
    const int ty = threadIdx.x >> 6;      // 0..3

    #pragma unroll 4
    for (int i = 0; i < 16; i++) {
        int cl = ty + i * 4;
        int c  = c0 + cl;
        const float* src = (c < C1)
            ? (F1 + ((size_t)b * C1 + c) * NN)
            : (F2 + ((size_t)b * C2 + (c - C1)) * NN);
        tile[cl][tx] = src[n0 + tx];
    }
    __syncthreads();
    #pragma unroll 4
    for (int i = 0; i < 16; i++) {
        int nl = ty + i * 4;
        Ft[((size_t)b * NN + (n0 + nl)) * CF + c0 + tx] = tile[tx][nl];
    }
}

// ---------------- kernel 4: pooled-global row per batch (j>=1124) ----------------
__global__ __launch_bounds__(256) void pg_kernel(
    const float* __restrict__ G, float* __restrict__ pg)
{
    int gid = blockIdx.x * 256 + threadIdx.x;
    int b   = gid / 2972;
    int jj  = gid % 2972;
    if (b >= BB) return;
    int j = 1124 + jj;
    int s = (j * CT) >> 12;
    int e = ((j + 1) * CT + (MM - 1)) >> 12;
    float v = G[(size_t)b * CG + (s - 387)];
    if (e - s > 1) v = fmaxf(v, G[(size_t)b * CG + (s - 386)]);
    pg[(size_t)b * MM + j] = v;
}

// ---------------- kernel 5: gather + interp + pool + write ----------------
__global__ __launch_bounds__(256) void interp_pool(
    const float* __restrict__ Q, const float* __restrict__ G,
    const float* __restrict__ Ft, const float* __restrict__ rec,
    const float* __restrict__ pg, float* __restrict__ out)
{
    __shared__ float agg[392];
    __shared__ float srec[8];
    const int t  = threadIdx.x;
    const int mg = blockIdx.x;
    const int b  = mg >> 12;
    const int m  = mg & (MM - 1);

    if (t < 8) srec[t] = rec[(size_t)mg * 8 + t];
    if (t == 8) agg[387] = G[(size_t)b * CG];
    if (t < 3) agg[t] = Q[(size_t)b * 3 * MM + t * MM + m];
    __syncthreads();

    const int i0 = __float_as_int(srec[0]);
    const int i1 = __float_as_int(srec[1]);
    const int i2 = __float_as_int(srec[2]);
    const float w0 = srec[3], w1 = srec[4], w2 = srec[5];
    const float* r0 = Ft + ((size_t)b * NN + i0) * CF;
    const float* r1 = Ft + ((size_t)b * NN + i1) * CF;
    const float* r2 = Ft + ((size_t)b * NN + i2) * CF;

    for (int c = t; c < CF; c += 256) {
        float v = __fadd_rn(__fadd_rn(__fmul_rn(r0[c], w0), __fmul_rn(r1[c], w1)),
                            __fmul_rn(r2[c], w2));
        agg[3 + c] = v;
    }
    __syncthreads();

    float4* out4 = (float4*)(out + (size_t)mg * MM);
    for (int g = t; g < 281; g += 256) {
        int j0 = g * 4;
        float4 o;
        float* op = &o.x;
        #pragma unroll
        for (int u = 0; u < 4; u++) {
            int j = j0 + u;
            int s = (j * CT) >> 12;
            int e = ((j + 1) * CT + (MM - 1)) >> 12;
            float v = agg[s];
            if (e - s > 1) v = fmaxf(v, agg[s + 1]);
            op[u] = v;
        }
        out4[g] = o;
    }
    const float4* pg4 = (const float4*)(pg + (size_t)b * MM);
    for (int g = t; g < 743; g += 256) {
        out4[281 + g] = pg4[281 + g];
    }
}

extern "C" void kernel_launch(void* const* d_in, const int* in_sizes, int n_in,
                              void* d_out, int out_size, void* d_ws, size_t ws_size,
                              hipStream_t stream) {
    (void)in_sizes; (void)n_in; (void)out_size;
    const float* P  = (const float*)d_in[0];
    const float* Q  = (const float*)d_in[1];
    const float* F1 = (const float*)d_in[2];
    const float* F2 = (const float*)d_in[3];
    const float* G  = (const float*)d_in[4];
    float* out = (float*)d_out;

    // Ft occupies [0, sz_ft). P4 + partials alias INSIDE the Ft region:
    // dead after knn_merge; transpose_feats (writes Ft) runs after it.
    const size_t off_ft  = 0;
    const size_t sz_ft   = (size_t)BB * NN * CF * 4;        // 50,331,648
    const size_t off_pg  = off_ft + sz_ft;
    const size_t sz_pg   = (size_t)BB * MM * 4;             // 32,768
    const size_t off_rec = off_pg + sz_pg;
    const size_t sz_rec  = (size_t)BB * MM * 8 * 4;         // 262,144
    const size_t need    = off_rec + sz_rec;                // 50,626,560

    const size_t off_p4  = 0;                               // aliases Ft
    const size_t sz_p4   = (size_t)BB * NN * 16;            // 524,288
    const size_t off_pd  = off_p4 + sz_p4;
    const size_t sz_pd   = (size_t)SPLIT * BB * MM * 16;    // 8,388,608
    const size_t off_pi  = off_pd + sz_pd;                  // ends ~17.3 MB < 50.3 MB

    if (ws_size >= need) {
        float4* P4  = (float4*)((char*)d_ws + off_p4);
        float4* pdb = (float4*)((char*)d_ws + off_pd);
        int4*   pib = (int4*)((char*)d_ws + off_pi);
        float*  Ft  = (float*)((char*)d_ws + off_ft);
        float*  pg  = (float*)((char*)d_ws + off_pg);
        float*  rec = (float*)((char*)d_ws + off_rec);

        hipLaunchKernelGGL(prep_p4,    dim3(BB * NN / 256), dim3(256), 0, stream, P, P4);
        hipLaunchKernelGGL(knn_scan,   dim3(128 * (SPLIT / 4)), dim3(256), 0, stream, P4, Q, pdb, pib);
        hipLaunchKernelGGL(knn_merge,  dim3(BB * MM / 256), dim3(256), 0, stream, P4, Q, pdb, pib, rec);
        hipLaunchKernelGGL(transpose_feats, dim3(BB * (NN / 64) * (CF / 64)), dim3(256), 0, stream, F1, F2, Ft);
        hipLaunchKernelGGL(pg_kernel,  dim3((BB * 2972 + 255) / 256), dim3(256), 0, stream, G, pg);
        hipLaunchKernelGGL(interp_pool, dim3(BB * MM), dim3(256), 0, stream, Q, G, Ft, rec, pg, out);
    } else {
        hipLaunchKernelGGL(p2p_fused, dim3(BB * MM), dim3(256), 0, stream, P, Q, F1, F2, G, out);
    }
}

// Round 5
// 118.928 us; speedup vs baseline: 2.4042x; 1.3130x over previous
//
#include <hip/hip_runtime.h>

#define BB 2
#define NN 16384
#define MM 4096
#define C1 128
#define C2 256
#define CF 384    // C1+C2
#define CG 1024
#define CT 1411   // 3 + 384 + 1024
#define FLTMAX 3.402823466e+38f
#define SPLIT 64             // point-splits per query (== wave width)
#define PTS_PER (NN / SPLIT) // 256 points per wave-scan

// ---------------- fallback (round-1) kernel ----------------
__global__ __launch_bounds__(256) void p2p_fused(
    const float* __restrict__ P, const float* __restrict__ Q,
    const float* __restrict__ F1, const float* __restrict__ F2,
    const float* __restrict__ G, float* __restrict__ out)
{
    const int t  = threadIdx.x;
    const int bm = blockIdx.x;
    const int b  = bm >> 12;
    const int m  = bm & (MM - 1);

    const float* Pb = P + (size_t)b * 3 * NN;
    const float qx = Q[(size_t)b * 3 * MM + 0 * MM + m];
    const float qy = Q[(size_t)b * 3 * MM + 1 * MM + m];
    const float qz = Q[(size_t)b * 3 * MM + 2 * MM + m];
    const float q2 = __fadd_rn(__fadd_rn(__fmul_rn(qx, qx), __fmul_rn(qy, qy)),
                               __fmul_rn(qz, qz));

    float bd0 = FLTMAX, bd1 = FLTMAX, bd2 = FLTMAX;
    int   bi0 = 0x7fffffff, bi1 = 0x7fffffff, bi2 = 0x7fffffff;

    for (int n = t; n < NN; n += 256) {
        float px = Pb[n];
        float py = Pb[NN + n];
        float pz = Pb[2 * NN + n];
        float p2 = __fadd_rn(__fadd_rn(__fmul_rn(px, px), __fmul_rn(py, py)),
                             __fmul_rn(pz, pz));
        float qp = __fadd_rn(__fadd_rn(__fmul_rn(qx, px), __fmul_rn(qy, py)),
                             __fmul_rn(qz, pz));
        float d2 = __fsub_rn(__fadd_rn(q2, p2), __fadd_rn(qp, qp));
        if (d2 < bd2) {
            if (d2 < bd1) {
                if (d2 < bd0) { bd2 = bd1; bi2 = bi1; bd1 = bd0; bi1 = bi0; bd0 = d2; bi0 = n; }
                else          { bd2 = bd1; bi2 = bi1; bd1 = d2;  bi1 = n; }
            } else            { bd2 = d2;  bi2 = n; }
        }
    }

    __shared__ float sd[256][3];
    __shared__ int   si[256][3];
    sd[t][0] = bd0; sd[t][1] = bd1; sd[t][2] = bd2;
    si[t][0] = bi0; si[t][1] = bi1; si[t][2] = bi2;
    __syncthreads();

    for (int off = 128; off >= 1; off >>= 1) {
        if (t < off) {
            float A[3]  = { sd[t][0], sd[t][1], sd[t][2] };
            int   AI[3] = { si[t][0], si[t][1], si[t][2] };
            float Bv[3] = { sd[t + off][0], sd[t + off][1], sd[t + off][2] };
            int   BI[3] = { si[t + off][0], si[t + off][1], si[t + off][2] };
            float rd[3]; int ri[3];
            int pa = 0, pb = 0;
            #pragma unroll
            for (int r = 0; r < 3; r++) {
                bool ta = (A[pa] < Bv[pb]) || (A[pa] == Bv[pb] && AI[pa] < BI[pb]);
                if (ta) { rd[r] = A[pa];  ri[r] = AI[pa]; pa++; }
                else    { rd[r] = Bv[pb]; ri[r] = BI[pb]; pb++; }
            }
            sd[t][0] = rd[0]; sd[t][1] = rd[1]; sd[t][2] = rd[2];
            si[t][0] = ri[0]; si[t][1] = ri[1]; si[t][2] = ri[2];
        }
        __syncthreads();
    }

    __shared__ float wsh[3];
    __shared__ int   ish[3];
    __shared__ float agg[CT + 1];

    if (t == 0) {
        float w[3];
        #pragma unroll
        for (int k = 0; k < 3; k++) {
            int i = si[0][k];
            ish[k] = i;
            float dx = __fsub_rn(Pb[i],          qx);
            float dy = __fsub_rn(Pb[NN + i],     qy);
            float dz = __fsub_rn(Pb[2 * NN + i], qz);
            float ds = __fadd_rn(__fadd_rn(__fmul_rn(dx, dx), __fmul_rn(dy, dy)),
                                 __fmul_rn(dz, dz));
            w[k] = expf(-0.5f * ds);
        }
        float Z = __fadd_rn(__fadd_rn(w[0], w[1]), w[2]);
        wsh[0] = w[0] / Z; wsh[1] = w[1] / Z; wsh[2] = w[2] / Z;
    }
    __syncthreads();

    const int   i0 = ish[0], i1 = ish[1], i2 = ish[2];
    const float w0 = wsh[0], w1 = wsh[1], w2 = wsh[2];

    if (t < 3) agg[t] = (t == 0) ? qx : ((t == 1) ? qy : qz);

    for (int c = t; c < C1 + C2; c += 256) {
        const float* base = (c < C1)
            ? (F1 + ((size_t)b * C1 + c) * NN)
            : (F2 + ((size_t)b * C2 + (c - C1)) * NN);
        float f0 = base[i0], f1 = base[i1], f2 = base[i2];
        float v = __fadd_rn(__fadd_rn(__fmul_rn(f0, w0), __fmul_rn(f1, w1)),
                            __fmul_rn(f2, w2));
        agg[3 + c] = v;
    }
    for (int c = t; c < CG; c += 256) {
        agg[3 + C1 + C2 + c] = G[(size_t)b * CG + c];
    }
    __syncthreads();

    float* orow = out + ((size_t)b * MM + m) * MM;
    for (int j = t; j < MM; j += 256) {
        int s = (j * CT) >> 12;
        int e = ((j + 1) * CT + (MM - 1)) >> 12;
        float v = agg[s];
        if (e - s > 1) v = fmaxf(v, agg[s + 1]);
        orow[j] = v;
    }
}

// ---------------- kernel A: fused prep (transpose + P4 pack + pg row) ------
__global__ __launch_bounds__(256) void prep_all(
    const float* __restrict__ P,  const float* __restrict__ F1,
    const float* __restrict__ F2, const float* __restrict__ G,
    float4* __restrict__ P4, float* __restrict__ Ft, float* __restrict__ pg)
{
    __shared__ float tile[64][65];
    const int blk = blockIdx.x;
    const int t   = threadIdx.x;

    if (blk < 3072) {
        // transpose F1,F2 -> Ft[b][n][384]
        const int b  = blk / 1536;
        const int r  = blk % 1536;
        const int ct = r / 256;               // 0..5
        const int nt = r % 256;               // 0..255
        const int c0 = ct * 64, n0 = nt * 64;
        const int tx = t & 63;
        const int ty = t >> 6;                // 0..3

        #pragma unroll 4
        for (int i = 0; i < 16; i++) {
            int cl = ty + i * 4;
            int c  = c0 + cl;
            const float* src = (c < C1)
                ? (F1 + ((size_t)b * C1 + c) * NN)
                : (F2 + ((size_t)b * C2 + (c - C1)) * NN);
            tile[cl][tx] = src[n0 + tx];
        }
        __syncthreads();
        #pragma unroll 4
        for (int i = 0; i < 16; i++) {
            int nl = ty + i * 4;
            Ft[((size_t)b * NN + (n0 + nl)) * CF + c0 + tx] = tile[tx][nl];
        }
    } else if (blk < 3200) {
        // P4 = (x,y,z,p2)
        int gid = (blk - 3072) * 256 + t;     // 0 .. BB*NN-1
        int b   = gid >> 14;
        int n   = gid & (NN - 1);
        const float* Pb = P + (size_t)b * 3 * NN;
        float x = Pb[n], y = Pb[NN + n], z = Pb[2 * NN + n];
        float p2 = __fadd_rn(__fadd_rn(__fmul_rn(x, x), __fmul_rn(y, y)),
                             __fmul_rn(z, z));
        P4[gid] = make_float4(x, y, z, p2);
    } else {
        // pooled-global row (j >= 1124), once per batch
        int gid = (blk - 3200) * 256 + t;
        int b   = gid / 2972;
        int jj  = gid % 2972;
        if (b < BB) {
            int j = 1124 + jj;
            int s = (j * CT) >> 12;
            int e = ((j + 1) * CT + (MM - 1)) >> 12;
            float v = G[(size_t)b * CG + (s - 387)];
            if (e - s > 1) v = fmaxf(v, G[(size_t)b * CG + (s - 386)]);
            pg[(size_t)b * MM + j] = v;
        }
    }
}

// exact-rn distance, identical rounding to the np reference expansion
__device__ __forceinline__ float dist_rn(float qx, float qy, float qz, float q2,
                                         float4 v)
{
    float qp = __fadd_rn(__fadd_rn(__fmul_rn(qx, v.x), __fmul_rn(qy, v.y)),
                         __fmul_rn(qz, v.z));
    return __fsub_rn(__fadd_rn(q2, v.w), __fadd_rn(qp, qp));
}

// branchless sorted insert, strict < (within-split: scan order = ascending n)
#define INS(dv, nv)                                                          \
    {                                                                        \
        bool c0 = (dv) < b0, c1 = (dv) < b1, c2 = (dv) < b2;                 \
        float nb2 = c1 ? b1 : (c2 ? (dv) : b2);                              \
        int   ni2 = c1 ? i1 : (c2 ? (nv) : i2);                              \
        float nb1 = c0 ? b0 : (c1 ? (dv) : b1);                              \
        int   ni1 = c0 ? i0 : (c1 ? (nv) : i1);                              \
        float nb0 = c0 ? (dv) : b0;                                          \
        int   ni0 = c0 ? (nv) : i0;                                          \
        b0 = nb0; b1 = nb1; b2 = nb2; i0 = ni0; i1 = ni1; i2 = ni2;          \
    }

// lexicographic (d, idx) insert — cross-split merge (== top_k stability)
#define INSL(dv, nv)                                                         \
    {                                                                        \
        bool c0 = ((dv) < b0) || ((dv) == b0 && (nv) < i0);                  \
        bool c1 = ((dv) < b1) || ((dv) == b1 && (nv) < i1);                  \
        bool c2 = ((dv) < b2) || ((dv) == b2 && (nv) < i2);                  \
        float nb2 = c1 ? b1 : (c2 ? (dv) : b2);                              \
        int   ni2 = c1 ? i1 : (c2 ? (nv) : i2);                              \
        float nb1 = c0 ? b0 : (c1 ? (dv) : b1);                              \
        int   ni1 = c0 ? i0 : (c1 ? (nv) : i1);                              \
        float nb0 = c0 ? (dv) : b0;                                          \
        int   ni0 = c0 ? (nv) : i0;                                          \
        b0 = nb0; b1 = nb1; b2 = nb2; i0 = ni0; i1 = ni1; i2 = ni2;          \
    }

// ---------------- kernel B: kNN scan, query-per-lane, 4-pt tournament ------
// grid: 2048 blocks x 256. block = (qg 0..127, ps 0..15); wave wv 0..3.
// split sp = ps*4+wv scans points [sp*256, sp*256+256) for 64 queries.
// partials at [query][split] (contiguous per query) for coalesced merge.
__global__ __launch_bounds__(256) void knn_scan(
    const float4* __restrict__ P4, const float* __restrict__ Q,
    float4* __restrict__ pd, int4* __restrict__ pi)
{
    const int t    = threadIdx.x;
    const int lane = t & 63;
    const int wv   = __builtin_amdgcn_readfirstlane(t >> 6);
    const int qg   = blockIdx.x & 127;
    const int ps   = blockIdx.x >> 7;
    const int sp   = ps * 4 + wv;
    const int mg   = qg * 64 + lane;
    const int b    = qg >> 6;
    const int m    = mg & (MM - 1);

    const float qx = Q[(size_t)b * 3 * MM + m];
    const float qy = Q[(size_t)b * 3 * MM + MM + m];
    const float qz = Q[(size_t)b * 3 * MM + 2 * MM + m];
    const float q2 = __fadd_rn(__fadd_rn(__fmul_rn(qx, qx), __fmul_rn(qy, qy)),
                               __fmul_rn(qz, qz));

    const float4* Pw = P4 + b * NN + sp * PTS_PER;  // wave-uniform base
    const int nbase = sp * PTS_PER;

    float b0 = FLTMAX, b1 = FLTMAX, b2 = FLTMAX;
    int   i0 = 0x7fffffff, i1 = 0x7fffffff, i2 = 0x7fffffff;

    #pragma unroll 4
    for (int g = 0; g < PTS_PER; g += 4) {
        float4 v0 = Pw[g + 0];
        float4 v1 = Pw[g + 1];
        float4 v2 = Pw[g + 2];
        float4 v3 = Pw[g + 3];
        float d0  = dist_rn(qx, qy, qz, q2, v0);
        float d1  = dist_rn(qx, qy, qz, q2, v1);
        float d2v = dist_rn(qx, qy, qz, q2, v2);
        float d3  = dist_rn(qx, qy, qz, q2, v3);

        // min4 with index (ties -> lower u, matching ascending-n stability)
        bool  cA = d1 < d0;   float mA = fminf(d0, d1);   int uA = cA ? 1 : 0;
        bool  cB = d3 < d2v;  float mB = fminf(d2v, d3);  int uB = cB ? 3 : 2;
        bool  cF = mB < mA;   float mF = fminf(mA, mB);   int uF = cF ? uB : uA;
        int nmin = nbase + g + uF;

        // second smallest of the 4 (exactness fixup trigger)
        float MA = fmaxf(d0, d1), MB = fmaxf(d2v, d3);
        float sec = fminf(cF ? mA : mB, cF ? MB : MA);

        INS(mF, nmin);

        if (sec < b2) {  // rare: group holds >=2 of the running top-3
            #pragma unroll
            for (int u = 0; u < 4; u++) {
                float du = (u == 0) ? d0 : ((u == 1) ? d1 : ((u == 2) ? d2v : d3));
                if (uF != u) {
                    INS(du, nbase + g + u);
                }
            }
        }
    }

    int o = (mg << 6) + sp;     // [query][split]
    pd[o] = make_float4(b0, b1, b2, 0.0f);
    pi[o] = make_int4(i0, i1, i2, 0);
}

// ---------------- kernel C: butterfly merge + interp + pool + write --------
// one block (256 thr) per query. wave 0: merge 64 split-triples via shfl_xor,
// compute Gaussian weights. waves 1-3: copy pooled-global region. then all:
// interp 384 channels + pool j<1124.
__global__ __launch_bounds__(256) void merge_interp_pool(
    const float4* __restrict__ P4, const float* __restrict__ Q,
    const float* __restrict__ G, const float* __restrict__ Ft,
    const float4* __restrict__ pd, const int4* __restrict__ pi,
    const float* __restrict__ pg, float* __restrict__ out)
{
    __shared__ float agg[392];
    __shared__ float swt[3];
    __shared__ int   sidm[3];

    const int t  = threadIdx.x;
    const int mg = blockIdx.x;
    const int b  = mg >> 12;
    const int m  = mg & (MM - 1);

    float4* out4 = (float4*)(out + (size_t)mg * MM);

    if (t < 64) {
        // ---- wave 0: merge + weights ----
        const int lane = t;
        float4 d4 = pd[(mg << 6) + lane];
        int4   i4 = pi[(mg << 6) + lane];
        float b0 = d4.x, b1 = d4.y, b2 = d4.z;
        int   i0 = i4.x, i1 = i4.y, i2 = i4.z;

        #pragma unroll
        for (int mask = 1; mask < 64; mask <<= 1) {
            float e0 = __shfl_xor(b0, mask);
            float e1 = __shfl_xor(b1, mask);
            float e2 = __shfl_xor(b2, mask);
            int   j0 = __shfl_xor(i0, mask);
            int   j1 = __shfl_xor(i1, mask);
            int   j2 = __shfl_xor(i2, mask);
            INSL(e0, j0);
            INSL(e1, j1);
            INSL(e2, j2);
        }

        // lanes 0-2: Gaussian weight for neighbor k=lane (direct-form dist)
        int myid = (lane == 0) ? i0 : ((lane == 1) ? i1 : i2);
        float w = 0.0f;
        if (lane < 3) {
            float qx = Q[(size_t)b * 3 * MM + m];
            float qy = Q[(size_t)b * 3 * MM + MM + m];
            float qz = Q[(size_t)b * 3 * MM + 2 * MM + m];
            float4 pv = P4[b * NN + myid];
            float dx = __fsub_rn(pv.x, qx);
            float dy = __fsub_rn(pv.y, qy);
            float dz = __fsub_rn(pv.z, qz);
            float ds = __fadd_rn(__fadd_rn(__fmul_rn(dx, dx), __fmul_rn(dy, dy)),
                                 __fmul_rn(dz, dz));
            w = expf(-0.5f * ds);
        }
        float wA = __shfl(w, 0);
        float wB = __shfl(w, 1);
        float wC = __shfl(w, 2);
        if (lane < 3) {
            float Z = __fadd_rn(__fadd_rn(wA, wB), wC);
            swt[lane]  = w / Z;
            sidm[lane] = myid;
        }
    } else {
        // ---- waves 1-3: query coords, agg[387], pooled-global copy ----
        if (t >= 65 && t < 68) {
            agg[t - 65] = Q[(size_t)b * 3 * MM + (size_t)(t - 65) * MM + m];
        }
        if (t == 64) agg[387] = G[(size_t)b * CG];
        const float4* pg4 = (const float4*)(pg + (size_t)b * MM);
        for (int g = t - 64; g < 743; g += 192) {
            out4[281 + g] = pg4[281 + g];
        }
    }
    __syncthreads();

    const int   i0 = sidm[0], i1 = sidm[1], i2 = sidm[2];
    const float w0 = swt[0],  w1 = swt[1],  w2 = swt[2];
    const float* r0 = Ft + ((size_t)b * NN + i0) * CF;
    const float* r1 = Ft + ((size_t)b * NN + i1) * CF;
    const float* r2 = Ft + ((size_t)b * NN + i2) * CF;

    for (int c = t; c < CF; c += 256) {
        float v = __fadd_rn(__fadd_rn(__fmul_rn(r0[c], w0), __fmul_rn(r1[c], w1)),
                            __fmul_rn(r2[c], w2));
        agg[3 + c] = v;
    }
    __syncthreads();

    for (int g = t; g < 281; g += 256) {
        int j0 = g * 4;
        float4 o;
        float* op = &o.x;
        #pragma unroll
        for (int u = 0; u < 4; u++) {
            int j = j0 + u;
            int s = (j * CT) >> 12;
            int e = ((j + 1) * CT + (MM - 1)) >> 12;
            float v = agg[s];
            if (e - s > 1) v = fmaxf(v, agg[s + 1]);
            op[u] = v;
        }
        out4[g] = o;
    }
}

extern "C" void kernel_launch(void* const* d_in, const int* in_sizes, int n_in,
                              void* d_out, int out_size, void* d_ws, size_t ws_size,
                              hipStream_t stream) {
    (void)in_sizes; (void)n_in; (void)out_size;
    const float* P  = (const float*)d_in[0];
    const float* Q  = (const float*)d_in[1];
    const float* F1 = (const float*)d_in[2];
    const float* F2 = (const float*)d_in[3];
    const float* G  = (const float*)d_in[4];
    float* out = (float*)d_out;

    // no aliasing: ws is large (512 MiB fill observed in profile)
    const size_t off_ft  = 0;
    const size_t sz_ft   = (size_t)BB * NN * CF * 4;        // 50,331,648
    const size_t off_p4  = off_ft + sz_ft;
    const size_t sz_p4   = (size_t)BB * NN * 16;            // 524,288
    const size_t off_pd  = off_p4 + sz_p4;
    const size_t sz_pd   = (size_t)BB * MM * SPLIT * 16;    // 8,388,608
    const size_t off_pi  = off_pd + sz_pd;
    const size_t sz_pi   = sz_pd;                           // 8,388,608
    const size_t off_pg  = off_pi + sz_pi;
    const size_t sz_pg   = (size_t)BB * MM * 4;             // 32,768
    const size_t need    = off_pg + sz_pg;                  // ~67.7 MB

    if (ws_size >= need) {
        float*  Ft  = (float*)((char*)d_ws + off_ft);
        float4* P4  = (float4*)((char*)d_ws + off_p4);
        float4* pdb = (float4*)((char*)d_ws + off_pd);
        int4*   pib = (int4*)((char*)d_ws + off_pi);
        float*  pg  = (float*)((char*)d_ws + off_pg);

        hipLaunchKernelGGL(prep_all, dim3(3072 + 128 + 24), dim3(256), 0, stream,
                           P, F1, F2, G, P4, Ft, pg);
        hipLaunchKernelGGL(knn_scan, dim3(128 * (SPLIT / 4)), dim3(256), 0, stream,
                           P4, Q, pdb, pib);
        hipLaunchKernelGGL(merge_interp_pool, dim3(BB * MM), dim3(256), 0, stream,
                           P4, Q, G, Ft, pdb, pib, pg, out);
    } else {
        hipLaunchKernelGGL(p2p_fused, dim3(BB * MM), dim3(256), 0, stream,
                           P, Q, F1, F2, G, out);
    }
}